// Round 13
// baseline (155.949 us; speedup 1.0000x reference)
//
#include <hip/hip_runtime.h>
#include <hip/hip_bf16.h>

#define T_LEN 2048
#define D_DIM 128
#define K_DIM 2048
#define M_DIM 8192
#define LOOKUP 101
#define HWIN 50

typedef __attribute__((ext_vector_type(8))) short short8;
typedef __attribute__((ext_vector_type(4))) float f32x4;

static __device__ __forceinline__ unsigned int f2bf(float f) {
  unsigned int u = __float_as_uint(f);
  return (u + 0x7fffu + ((u >> 16) & 1u)) >> 16;  // RNE bf16 bits
}

static __device__ __forceinline__ short8 pack8(float4 lo, float4 hi) {
  uint4 u;
  u.x = f2bf(lo.x) | (f2bf(lo.y) << 16);
  u.y = f2bf(lo.z) | (f2bf(lo.w) << 16);
  u.z = f2bf(hi.x) | (f2bf(hi.y) << 16);
  u.w = f2bf(hi.z) | (f2bf(hi.w) << 16);
  return *(short8*)&u;
}

typedef __attribute__((address_space(3))) unsigned char lds_uchar;
typedef const __attribute__((address_space(1))) unsigned char g_uchar;
static __device__ __forceinline__ void gll16(const void* g, void* l) {
  __builtin_amdgcn_global_load_lds((g_uchar*)g, (lds_uchar*)l, 16, 0, 0);
}

// ---- Kernel 0: zero the 4 MB f32 accumulator (exactly 1M floats) ----
__global__ __launch_bounds__(256) void k_zero(float* __restrict__ acc) {
  const int i = blockIdx.x * 256 + threadIdx.x;  // 0..65535
  float4 z = make_float4(0.f, 0.f, 0.f, 0.f);
#pragma unroll
  for (int j = 0; j < 4; ++j) *(float4*)(acc + ((size_t)i + j * 65536) * 4) = z;
}

// ---- Kernel 1: W [2048][128] f32 -> Bp fragment-packed bf16 (512 KB) ----
// Bp region (ksg*8+ct), lane: 16B = bf16 of W[ksg*32 + (lane>>4)*8 + j][ct*16 + (lane&15)]
__global__ __launch_bounds__(256) void k_pack(const float* __restrict__ W,
                                              unsigned short* __restrict__ Bp) {
  __shared__ float sw[32][132];
  const int ks = blockIdx.x;  // 0..63
  const int t = threadIdx.x;
  const float* src = W + (size_t)ks * 32 * D_DIM;
#pragma unroll
  for (int j = 0; j < 4; ++j) {
    int idx = t + j * 256;
    int row = idx >> 5, c4 = idx & 31;
    float4 v = *(const float4*)(src + row * D_DIM + c4 * 4);
    *(float4*)&sw[row][c4 * 4] = v;
  }
  __syncthreads();
#pragma unroll
  for (int e = 0; e < 2; ++e) {
    int f = t * 2 + e;
    int ct = f >> 6, l = f & 63;
    int kr = (l >> 4) * 8, col = ct * 16 + (l & 15);
    uint4 o;
    o.x = f2bf(sw[kr + 0][col]) | (f2bf(sw[kr + 1][col]) << 16);
    o.y = f2bf(sw[kr + 2][col]) | (f2bf(sw[kr + 3][col]) << 16);
    o.z = f2bf(sw[kr + 4][col]) | (f2bf(sw[kr + 5][col]) << 16);
    o.w = f2bf(sw[kr + 6][col]) | (f2bf(sw[kr + 7][col]) << 16);
    *(uint4*)(Bp + (((size_t)(ks * 8 + ct) << 6) + l) * 8) = o;
  }
}

// ---- Kernel 2: k-sliced persistent-block GEMM. B-in-LDS ONCE, pure x streaming ----
// grid 256 = 1 block/CU. Block: ks = bid&7 (k in [ks*256,+256)), rows (bid>>3)*256..+256.
// Phase 0: B-slice 64KB -> LDS once; each wave hoists 8 W-frags (ct=wv) to registers.
// Main: 16 row-groups of 16; x staged via gll16 (1KB contig/instr, src-XOR) into 4x16KB
// ring, depth-2, vmcnt(4), 1 barrier/group; 8 MFMA/group/wave; acc all 16 groups in regs.
// End: 64 f32 atomicAdd per wave into global accum (cross-ks reduction).
__global__ __launch_bounds__(512, 2) void k_gemm(const float* __restrict__ X,
                                                 const unsigned short* __restrict__ Bp,
                                                 float* __restrict__ accum) {
  __shared__ __align__(16) unsigned char Bs[65536];
  __shared__ __align__(16) unsigned char xb[4][16384];
  const int tid = threadIdx.x;
  const int lane = tid & 63;
  const int wv = tid >> 6;      // col-tile ct = wv
  const int ks = blockIdx.x & 7;
  const int r0 = (blockIdx.x >> 3) * 256;
  const int l15 = lane & 15;
  const int kg = lane >> 4;

  // phase 0: stage B slice (64 regions x 1KB, contiguous), this wave: regions wv*8..+8
#pragma unroll
  for (int i = 0; i < 8; ++i) {
    int reg = wv * 8 + i;
    gll16(Bp + (size_t)ks * 32768 + reg * 512 + lane * 8, Bs + reg * 1024 + lane * 16);
  }
  // stage x groups 0,1 (each: 16 rows x 1KB; this wave rows wv*2, wv*2+1)
  auto stage = [&](int g) {
#pragma unroll
    for (int u = 0; u < 2; ++u) {
      int rl = wv * 2 + u;                     // row within group
      int gs = lane ^ (rl & 7);                // source granule pre-swizzle
      gll16(X + (size_t)(r0 + g * 16 + rl) * K_DIM + ks * 256 + gs * 4,
            xb[g & 3] + rl * 1024 + lane * 16);
    }
  };
  stage(0);
  stage(1);
  asm volatile("s_waitcnt vmcnt(4)" ::: "memory");  // B landed (x 0,1 still in flight)
  __builtin_amdgcn_s_barrier();

  // hoist this wave's 8 W-frags from LDS
  short8 wf[8];
#pragma unroll
  for (int q = 0; q < 8; ++q)
    wf[q] = *(const short8*)(Bs + (q * 8 + wv) * 1024 + lane * 16);

  f32x4 acc[16];
#pragma unroll
  for (int i = 0; i < 16; ++i) acc[i] = (f32x4){0.f, 0.f, 0.f, 0.f};

#pragma unroll
  for (int g = 0; g < 16; ++g) {
    if (g + 2 < 16) stage(g + 2);
    if (g <= 13) {
      asm volatile("s_waitcnt vmcnt(4)" ::: "memory");
    } else if (g == 14) {
      asm volatile("s_waitcnt vmcnt(2)" ::: "memory");
    } else {
      asm volatile("s_waitcnt vmcnt(0)" ::: "memory");
    }
    __builtin_amdgcn_s_barrier();
    const unsigned char* xg = xb[g & 3];
    __builtin_amdgcn_s_setprio(1);
#pragma unroll
    for (int q = 0; q < 8; ++q) {
      int glo = (q * 8 + kg * 2) ^ (l15 & 7);
      int ghi = (q * 8 + kg * 2 + 1) ^ (l15 & 7);
      float4 alo = *(const float4*)(xg + l15 * 1024 + glo * 16);
      float4 ahi = *(const float4*)(xg + l15 * 1024 + ghi * 16);
      short8 xf = pack8(alo, ahi);
      acc[g] = __builtin_amdgcn_mfma_f32_16x16x32_bf16(wf[q], xf, acc[g], 0, 0, 0);
    }
    __builtin_amdgcn_s_setprio(0);
  }

  // cross-ks reduction: acc[g][j] = p[row = r0+g*16+l15][col = wv*16 + kg*4 + j]
#pragma unroll
  for (int g = 0; g < 16; ++g) {
    float* dst = accum + (size_t)(r0 + g * 16 + l15) * D_DIM + wv * 16 + kg * 4;
#pragma unroll
    for (int j = 0; j < 4; ++j) atomicAdd(dst + j, acc[g][j]);
  }
}

// ---- Kernel 2b: bias + row-normalize accum -> Pn bf16 ----
__global__ __launch_bounds__(256) void k_norm(const float* __restrict__ accum,
                                              const float* __restrict__ bias,
                                              unsigned short* __restrict__ Pn) {
  const int tid = threadIdx.x;
  const int row = blockIdx.x * 16 + (tid >> 4);
  const int c8 = tid & 15;
  float4 v0 = *(const float4*)(accum + (size_t)row * D_DIM + c8 * 8);
  float4 v1 = *(const float4*)(accum + (size_t)row * D_DIM + c8 * 8 + 4);
  float4 bv0 = *(const float4*)(bias + c8 * 8);
  float4 bv1 = *(const float4*)(bias + c8 * 8 + 4);
  float tot[8] = {v0.x + bv0.x, v0.y + bv0.y, v0.z + bv0.z, v0.w + bv0.w,
                  v1.x + bv1.x, v1.y + bv1.y, v1.z + bv1.z, v1.w + bv1.w};
  float ss = 0.f;
#pragma unroll
  for (int i = 0; i < 8; ++i) ss += tot[i] * tot[i];
  ss += __shfl_xor(ss, 1);
  ss += __shfl_xor(ss, 2);
  ss += __shfl_xor(ss, 4);
  ss += __shfl_xor(ss, 8);
  float sc = 1.0f / fmaxf(sqrtf(ss), 1e-12f);
  uint4 o;
  o.x = f2bf(tot[0] * sc) | (f2bf(tot[1] * sc) << 16);
  o.y = f2bf(tot[2] * sc) | (f2bf(tot[3] * sc) << 16);
  o.z = f2bf(tot[4] * sc) | (f2bf(tot[5] * sc) << 16);
  o.w = f2bf(tot[6] * sc) | (f2bf(tot[7] * sc) << 16);
  *(uint4*)(Pn + (size_t)row * D_DIM + c8 * 8) = o;
}

// ---------------- Kernel 3: banded similarity via MFMA ----------------
#define SROWS 144

__global__ __launch_bounds__(256) void k_sim(const unsigned short* __restrict__ Pn,
                                             float* __restrict__ out) {
  __shared__ unsigned short sm[SROWS * D_DIM];  // 36 KiB, XOR-swizzled 8-short groups
  const int bb = blockIdx.x >> 6;
  const int tb = blockIdx.x & 63;
  const int t0 = tb * 32;
  const int tid = threadIdx.x;

  for (int idx = tid; idx < SROWS * 16; idx += 256) {
    int i = idx >> 4, seg = idx & 15;
    int t = t0 - HWIN + i;
    uint4 val = make_uint4(0u, 0u, 0u, 0u);
    if (t >= 0 && t < T_LEN)
      val = *(const uint4*)(Pn + ((size_t)bb * T_LEN + t) * D_DIM + seg * 8);
    *(uint4*)&sm[i * D_DIM + ((seg ^ (i & 7)) << 3)] = val;
  }
  __syncthreads();

  const int lane = tid & 63;
  const int wv = tid >> 6;
  const int l15 = lane & 15;
  const int kg = lane >> 4;
  const int rt = wv >> 1;
  const int itp = wv & 1;

  short8 af[4];
  const int ia = HWIN + rt * 16 + l15;
#pragma unroll
  for (int ks = 0; ks < 4; ++ks) {
    int g = ks * 4 + kg;
    af[ks] = *(const short8*)&sm[ia * D_DIM + ((g ^ (ia & 7)) << 3)];
  }

  for (int it = itp; it < 9; it += 2) {
    f32x4 acc = (f32x4){0.f, 0.f, 0.f, 0.f};
    const int ib = it * 16 + l15;
#pragma unroll
    for (int ks = 0; ks < 4; ++ks) {
      int g = ks * 4 + kg;
      short8 bf = *(const short8*)&sm[ib * D_DIM + ((g ^ (ib & 7)) << 3)];
      acc = __builtin_amdgcn_mfma_f32_16x16x32_bf16(af[ks], bf, acc, 0, 0, 0);
    }
#pragma unroll
    for (int j = 0; j < 4; ++j) {
      int r = rt * 16 + kg * 4 + j;
      int w = ib - r;
      if (w >= 0 && w <= 100)
        out[((size_t)bb * T_LEN + t0 + r) * LOOKUP + w] = acc[j];
    }
  }
}

extern "C" void kernel_launch(void* const* d_in, const int* in_sizes, int n_in,
                              void* d_out, int out_size, void* d_ws, size_t ws_size,
                              hipStream_t stream) {
  (void)in_sizes; (void)n_in; (void)out_size; (void)ws_size;
  const float* x = (const float*)d_in[0];
  const float* W = (const float*)d_in[1];
  const float* b = (const float*)d_in[2];
  float* out = (float*)d_out;
  unsigned short* Bp = (unsigned short*)d_ws;            // 512 KiB fragment-packed W
  unsigned short* Pn = Bp + (size_t)D_DIM * K_DIM;       // 2 MiB bf16 normalized p
  float* accum = (float*)(Pn + (size_t)M_DIM * D_DIM);   // 4 MiB f32 accumulator

  k_zero<<<256, 256, 0, stream>>>(accum);
  k_pack<<<64, 256, 0, stream>>>(W, Bp);
  k_gemm<<<256, 512, 0, stream>>>(x, Bp, accum);
  k_norm<<<M_DIM / 16, 256, 0, stream>>>(accum, b, Pn);
  k_sim<<<4 * (T_LEN / 32), 256, 0, stream>>>(Pn, out);
}

// Round 15
// 66.874 us; speedup vs baseline: 2.3320x; 2.3320x over previous
//
#include <hip/hip_runtime.h>
#include <hip/hip_bf16.h>

#define T_LEN 2048
#define D_DIM 128
#define K_DIM 2048
#define M_DIM 8192
#define LOOKUP 101
#define HWIN 50

typedef __attribute__((ext_vector_type(8))) short short8;
typedef __attribute__((ext_vector_type(4))) float f32x4;

static __device__ __forceinline__ unsigned int f2bf(float f) {
  unsigned int u = __float_as_uint(f);
  return (u + 0x7fffu + ((u >> 16) & 1u)) >> 16;  // RNE bf16 bits
}

static __device__ __forceinline__ short8 pack8v(float4 lo, float4 hi) {
  union { short8 s; __hip_bfloat162 h[4]; } u;
  u.h[0] = __float22bfloat162_rn(make_float2(lo.x, lo.y));
  u.h[1] = __float22bfloat162_rn(make_float2(lo.z, lo.w));
  u.h[2] = __float22bfloat162_rn(make_float2(hi.x, hi.y));
  u.h[3] = __float22bfloat162_rn(make_float2(hi.z, hi.w));
  return u.s;
}

typedef __attribute__((address_space(3))) unsigned char lds_uchar;
typedef const __attribute__((address_space(1))) unsigned char g_uchar;
static __device__ __forceinline__ void gll16(const void* g, void* l) {
  __builtin_amdgcn_global_load_lds((g_uchar*)g, (lds_uchar*)l, 16, 0, 0);
}

// ---- Kernel 1: W [2048][128] f32 -> Bp fragment-packed bf16 (512 KB) ----
// Region (ksg*8+ct), lane: 16B = bf16 of W[ksg*32 + (lane>>4)*8 + j][ct*16 + (lane&15)]
__global__ __launch_bounds__(256) void k_pack(const float* __restrict__ W,
                                              unsigned short* __restrict__ Bp) {
  __shared__ float sw[32][132];
  const int ks = blockIdx.x;  // 0..63
  const int t = threadIdx.x;
  const float* src = W + (size_t)ks * 32 * D_DIM;
#pragma unroll
  for (int j = 0; j < 4; ++j) {
    int idx = t + j * 256;
    int row = idx >> 5, c4 = idx & 31;
    float4 v = *(const float4*)(src + row * D_DIM + c4 * 4);
    *(float4*)&sw[row][c4 * 4] = v;
  }
  __syncthreads();
#pragma unroll
  for (int e = 0; e < 2; ++e) {
    int f = t * 2 + e;
    int ct = f >> 6, l = f & 63;
    int kr = (l >> 4) * 8, col = ct * 16 + (l & 15);
    uint4 o;
    o.x = f2bf(sw[kr + 0][col]) | (f2bf(sw[kr + 1][col]) << 16);
    o.y = f2bf(sw[kr + 2][col]) | (f2bf(sw[kr + 3][col]) << 16);
    o.z = f2bf(sw[kr + 4][col]) | (f2bf(sw[kr + 5][col]) << 16);
    o.w = f2bf(sw[kr + 6][col]) | (f2bf(sw[kr + 7][col]) << 16);
    *(uint4*)(Bp + (((size_t)(ks * 8 + ct) << 6) + l) * 8) = o;
  }
}

// ---- Kernel 2: contiguous-row streaming GEMM, fused bias/norm ----
// grid 256 = 1 block/CU, 512 thr (8 waves = col-tiles). Block: rows r0..r0+31, full K.
// 4 phases: (rg 0/1 of 16 rows) x (k-half hA/hB; odd blocks swap half order).
// Phase buffer 64KB = 16 rows x 4KB contiguous runs staged by 64 gll16 (src granule-XOR).
// B: register double-buffer, 4 contiguous 1KB loads/chunk from L2-resident Bp.
// Steady s_waitcnt vmcnt(12); raw s_barrier only. acc = one f32x4/wave (full K).
__global__ __launch_bounds__(512) void k_gemm(const float* __restrict__ X,
                                              const unsigned short* __restrict__ Bp,
                                              const float* __restrict__ bias,
                                              unsigned short* __restrict__ Pn) {
  __shared__ __align__(16) unsigned char xb[2][65536];
  __shared__ __align__(16) unsigned char Pq[8192];
  const int tid = threadIdx.x;
  const int lane = tid & 63;
  const int wv = tid >> 6;      // col-tile 0..7
  const int r0 = blockIdx.x * 32;
  const int l15 = lane & 15;
  const int kg = lane >> 4;
  const int hA = blockIdx.x & 1;
  const int hB = hA ^ 1;

  // stage 16-row half-K buffer: 8 gll16/wave, each 1KB contiguous (quarter-row)
  auto stage = [&](int sl, int rgb, int h) {
#pragma unroll
    for (int i = 0; i < 8; ++i) {
      int id = wv * 8 + i;
      int row = id >> 2, kb = id & 3;
      const float* src = X + (size_t)(r0 + rgb + row) * K_DIM + h * 1024 + kb * 256 +
                         ((lane ^ (row & 7)) << 2);
      gll16(src, xb[sl] + row * 4096 + kb * 1024 + lane * 16);
    }
  };
#define LOADB(P, KB)                                                                  \
  {                                                                                   \
    _Pragma("unroll") for (int s = 0; s < 4; ++s)                                     \
        P[s] = *(const short8*)(Bp + (((size_t)((KB) + s) * 8 + wv) * 64 + lane) * 8); \
  }

  short8 ba[4], bb[4];
  f32x4 acc = (f32x4){0.f, 0.f, 0.f, 0.f};
  const float4 bvp = *(const float4*)(bias + (tid & 31) * 4);  // epilogue granule bias

  // prologue: queue = [stage(ph0):8][B(0):4] -> vmcnt(4) = stage done
  stage(0, 0, hA);
  LOADB(ba, hA * 32);
  asm volatile("s_waitcnt vmcnt(4)" ::: "memory");
  __builtin_amdgcn_s_barrier();
  __builtin_amdgcn_sched_barrier(0);

#pragma unroll
  for (int p = 0; p < 4; ++p) {
    const int sl = p & 1;
    if (p < 3) {  // stage next phase into other slot
      const int pn = p + 1;
      stage(pn & 1, (pn >> 1) * 16, (pn & 1) ? hB : hA);
    }
#pragma unroll
    for (int c = 0; c < 8; ++c) {
      const int t = p * 8 + c;
      // prefetch next chunk's B
      if (t < 31) {
        const int pn = (t + 1) >> 3, cn = (t + 1) & 7;
        const int hn = (pn & 1) ? hB : hA;
        if ((t & 1) == 0) LOADB(bb, hn * 32 + cn * 4)
        else              LOADB(ba, hn * 32 + cn * 4)
      }
      if (p < 3) {
        asm volatile("s_waitcnt vmcnt(12)" ::: "memory");
      } else if (c < 7) {
        asm volatile("s_waitcnt vmcnt(4)" ::: "memory");
      } else {
        asm volatile("s_waitcnt vmcnt(0)" ::: "memory");
      }
      const unsigned char* xgp = xb[sl] + l15 * 4096;
#pragma unroll
      for (int s = 0; s < 4; ++s) {
        int sg = c * 32 + s * 8 + kg * 2;
        float4 alo = *(const float4*)(xgp + ((sg ^ (l15 & 7)) << 4));
        float4 ahi = *(const float4*)(xgp + (((sg + 1) ^ (l15 & 7)) << 4));
        short8 xf = pack8v(alo, ahi);
        short8 wf = ((t & 1) == 0) ? ba[s] : bb[s];
        acc = __builtin_amdgcn_mfma_f32_16x16x32_bf16(wf, xf, acc, 0, 0, 0);
      }
    }
    if (p < 3) {
      asm volatile("s_waitcnt vmcnt(4)" ::: "memory");  // next-phase stage done
      __builtin_amdgcn_s_barrier();
      __builtin_amdgcn_sched_barrier(0);
    }
    if (p == 1 || p == 3) {
      // fused epilogue for rows rgb..rgb+15: Pq exchange + bias + norm + bf16 store
      const int rgb = (p >> 1) * 16;
      {
        int gq = wv * 4 + kg;
        int wbyte = l15 * 512 + ((gq << 4) ^ ((l15 & 7) << 4));
        *(float4*)(Pq + wbyte) = make_float4(acc[0], acc[1], acc[2], acc[3]);
      }
      asm volatile("s_waitcnt lgkmcnt(0)" ::: "memory");
      __builtin_amdgcn_s_barrier();
      __builtin_amdgcn_sched_barrier(0);
      {
        // 512 threads: 32 per row (16 rows), one 16B granule (4 cols) each
        int row = tid >> 5;   // 0..15
        int c4 = tid & 31;    // granule 0..31
        float4 v = *(const float4*)(Pq + row * 512 + ((c4 << 4) ^ ((row & 7) << 4)));
        float t0v = v.x + bvp.x, t1v = v.y + bvp.y, t2v = v.z + bvp.z, t3v = v.w + bvp.w;
        float ss = t0v * t0v + t1v * t1v + t2v * t2v + t3v * t3v;
        ss += __shfl_xor(ss, 1);
        ss += __shfl_xor(ss, 2);
        ss += __shfl_xor(ss, 4);
        ss += __shfl_xor(ss, 8);
        ss += __shfl_xor(ss, 16);
        float sc = 1.0f / fmaxf(sqrtf(ss), 1e-12f);
        uint2 o;
        o.x = f2bf(t0v * sc) | (f2bf(t1v * sc) << 16);
        o.y = f2bf(t2v * sc) | (f2bf(t3v * sc) << 16);
        *(uint2*)(Pn + (size_t)(r0 + rgb + row) * D_DIM + c4 * 4) = o;
      }
      acc = (f32x4){0.f, 0.f, 0.f, 0.f};
      __builtin_amdgcn_s_barrier();  // Pq reads done before any later reuse
    }
  }
}

// ---------------- Kernel 3: banded similarity via MFMA ----------------
#define SROWS 144

__global__ __launch_bounds__(256) void k_sim(const unsigned short* __restrict__ Pn,
                                             float* __restrict__ out) {
  __shared__ unsigned short sm[SROWS * D_DIM];  // 36 KiB, XOR-swizzled 8-short groups
  const int bb = blockIdx.x >> 6;
  const int tb = blockIdx.x & 63;
  const int t0 = tb * 32;
  const int tid = threadIdx.x;

  for (int idx = tid; idx < SROWS * 16; idx += 256) {
    int i = idx >> 4, seg = idx & 15;
    int t = t0 - HWIN + i;
    uint4 val = make_uint4(0u, 0u, 0u, 0u);
    if (t >= 0 && t < T_LEN)
      val = *(const uint4*)(Pn + ((size_t)bb * T_LEN + t) * D_DIM + seg * 8);
    *(uint4*)&sm[i * D_DIM + ((seg ^ (i & 7)) << 3)] = val;
  }
  __syncthreads();

  const int lane = tid & 63;
  const int wv = tid >> 6;
  const int l15 = lane & 15;
  const int kg = lane >> 4;
  const int rt = wv >> 1;
  const int itp = wv & 1;

  short8 af[4];
  const int ia = HWIN + rt * 16 + l15;
#pragma unroll
  for (int ks = 0; ks < 4; ++ks) {
    int g = ks * 4 + kg;
    af[ks] = *(const short8*)&sm[ia * D_DIM + ((g ^ (ia & 7)) << 3)];
  }

  for (int it = itp; it < 9; it += 2) {
    f32x4 acc = (f32x4){0.f, 0.f, 0.f, 0.f};
    const int ib = it * 16 + l15;
#pragma unroll
    for (int ks = 0; ks < 4; ++ks) {
      int g = ks * 4 + kg;
      short8 bf = *(const short8*)&sm[ib * D_DIM + ((g ^ (ib & 7)) << 3)];
      acc = __builtin_amdgcn_mfma_f32_16x16x32_bf16(af[ks], bf, acc, 0, 0, 0);
    }
#pragma unroll
    for (int j = 0; j < 4; ++j) {
      int r = rt * 16 + kg * 4 + j;
      int w = ib - r;
      if (w >= 0 && w <= 100)
        out[((size_t)bb * T_LEN + t0 + r) * LOOKUP + w] = acc[j];
    }
  }
}

extern "C" void kernel_launch(void* const* d_in, const int* in_sizes, int n_in,
                              void* d_out, int out_size, void* d_ws, size_t ws_size,
                              hipStream_t stream) {
  (void)in_sizes; (void)n_in; (void)out_size; (void)ws_size;
  const float* x = (const float*)d_in[0];
  const float* W = (const float*)d_in[1];
  const float* b = (const float*)d_in[2];
  float* out = (float*)d_out;
  unsigned short* Bp = (unsigned short*)d_ws;            // 512 KiB fragment-packed W
  unsigned short* Pn = Bp + (size_t)D_DIM * K_DIM;       // 2 MiB bf16 normalized p

  k_pack<<<64, 256, 0, stream>>>(W, Bp);
  k_gemm<<<M_DIM / 32, 512, 0, stream>>>(x, Bp, b, Pn);
  k_sim<<<4 * (T_LEN / 32), 256, 0, stream>>>(Pn, out);
}